// Round 14
// baseline (121.043 us; speedup 1.0000x reference)
//
#include <hip/hip_runtime.h>
#include <hip/hip_bf16.h>

// Problem constants: B=8, N=8192, S=2048, C1=128, C2=256, OUT=256
#define BB   8
#define NN   8192
#define SS   2048
#define C1C  128
#define C2C  256
#define KIN  384
#define OUTC 256

typedef __attribute__((ext_vector_type(4))) float f32x4;
typedef __attribute__((ext_vector_type(8))) short short8;
typedef __attribute__((ext_vector_type(8))) unsigned short ushortx8;

__device__ __forceinline__ ushort f2bf(float v) {
    __hip_bfloat16 h = __float2bfloat16(v);
    return __builtin_bit_cast(ushort, h);
}

__device__ __forceinline__ float med3(float a, float b, float c) {
    return __builtin_amdgcn_fmed3f(a, b, c);
}

// ---------------------------------------------------------------------------
// 3-NN scan (r11/r13-measured scan structure, VALU-issue-bound at max
// occupancy). THIS ROUND: gather phase REMOVED — kernel emits only
// (idx0..2, w0..2) per query into a 32B/query record (int4 + float4).
// The feat2 blend moves into gemm_fused's A-staging (kills the 67MB
// interp HBM round-trip).
// L=16 lanes/query, Q=2 queries/thread, 128 queries/block, 1024 threads,
// grid 512 = 2 blocks/CU = 8 waves/SIMD. Two-pass: branchless med3 value
// pass -> exact 3rd-smallest threshold -> rare-insert index pass (lex
// (f,idx) == stable lax.top_k).
// ---------------------------------------------------------------------------
__global__ __launch_bounds__(1024, 8) void knn_kernel(
    const float* __restrict__ xyz1, const float* __restrict__ xyz2,
    char* __restrict__ nnbuf)
{
    __shared__ float4 sp[SS];                     // 32 KB

    const int tid   = threadIdx.x;
    const int b     = blockIdx.x & 7;             // XCD-aligned batch
    const int chunk = blockIdx.x >> 3;            // 0..63
    const int qbase = chunk << 7;                 // 128 queries per block

    const float* x2 = xyz2 + (size_t)b * SS * 3;
    for (int i = tid; i < SS; i += 1024) {
        float x = x2[i*3+0], y = x2[i*3+1], z = x2[i*3+2];
        sp[i] = make_float4(-2.f*x, -2.f*y, -2.f*z, x*x + y*y + z*z);
    }
    __syncthreads();

    const int g = tid >> 4;                       // 0..63 (query pair)
    const int l = tid & 15;                       // lane within query
    const int qa = qbase + g * 2;

    const float* qp = xyz1 + ((size_t)b * NN + qa) * 3;
    float px[2] = {qp[0], qp[3]};
    float py[2] = {qp[1], qp[4]};
    float pz[2] = {qp[2], qp[5]};

    // ---------------- pass 1: top-3 values, branchless ----------------
    float c0[2], c1[2], c2[2];
#pragma unroll
    for (int qi = 0; qi < 2; ++qi) { c0[qi] = c1[qi] = c2[qi] = 1e30f; }

    for (int jj = 0; jj < 128; jj += 4) {
        float4 P[4];
#pragma unroll
        for (int u = 0; u < 4; ++u) P[u] = sp[((jj + u) << 4) + l];
#pragma unroll
        for (int u = 0; u < 4; ++u) {
#pragma unroll
            for (int qi = 0; qi < 2; ++qi) {
                float f = fmaf(px[qi], P[u].x,
                          fmaf(py[qi], P[u].y,
                          fmaf(pz[qi], P[u].z, P[u].w)));
                c2[qi] = med3(f, c1[qi], c2[qi]);
                c1[qi] = med3(f, c0[qi], c1[qi]);
                c0[qi] = fminf(f, c0[qi]);
            }
        }
    }

    // value-merge across the 16-lane group (multiset union top-3)
#pragma unroll
    for (int m = 1; m <= 8; m <<= 1) {
#pragma unroll
        for (int qi = 0; qi < 2; ++qi) {
            float b0 = __shfl_xor(c0[qi], m);
            float b1 = __shfl_xor(c1[qi], m);
            float b2 = __shfl_xor(c2[qi], m);
            float bv[3] = {b0, b1, b2};
#pragma unroll
            for (int e = 0; e < 3; ++e) {
                float d = bv[e];
                c2[qi] = med3(d, c1[qi], c2[qi]);
                c1[qi] = med3(d, c0[qi], c1[qi]);
                c0[qi] = fminf(d, c0[qi]);
            }
        }
    }
    const float t0 = c2[0], t1 = c2[1];           // exact 3rd-smallest scores

    // ---------------- pass 2: index recovery (rare inserts) ----------------
    float e0[2], e1[2], e2[2];
    int   i0[2], i1[2], i2[2];
#pragma unroll
    for (int qi = 0; qi < 2; ++qi) {
        e0[qi] = e1[qi] = e2[qi] = 1e30f;
        i0[qi] = i1[qi] = i2[qi] = 0x3fffffff;
    }

    for (int jj = 0; jj < 128; jj += 4) {
        float4 P[4];
#pragma unroll
        for (int u = 0; u < 4; ++u) P[u] = sp[((jj + u) << 4) + l];
#pragma unroll
        for (int u = 0; u < 4; ++u) {
            const int s = ((jj + u) << 4) + l;
#pragma unroll
            for (int qi = 0; qi < 2; ++qi) {
                float f = fmaf(px[qi], P[u].x,
                          fmaf(py[qi], P[u].y,
                          fmaf(pz[qi], P[u].z, P[u].w)));
                float tq = qi ? t1 : t0;
                if (f <= tq) {                     // ~3 hits per query total
                    bool lt2 = (f < e2[qi]) || (f == e2[qi] && s < i2[qi]);
                    if (lt2) {
                        bool lt1 = (f < e1[qi]) || (f == e1[qi] && s < i1[qi]);
                        bool lt0 = (f < e0[qi]) || (f == e0[qi] && s < i0[qi]);
                        e2[qi] = lt1 ? e1[qi] : f;  i2[qi] = lt1 ? i1[qi] : s;
                        e1[qi] = lt0 ? e0[qi] : (lt1 ? f : e1[qi]);
                        i1[qi] = lt0 ? i0[qi] : (lt1 ? s : i1[qi]);
                        e0[qi] = lt0 ? f : e0[qi];  i0[qi] = lt0 ? s : i0[qi];
                    }
                }
            }
        }
    }

    // lex merge across the 16-lane group
#pragma unroll
    for (int m = 1; m <= 8; m <<= 1) {
#pragma unroll
        for (int qi = 0; qi < 2; ++qi) {
            float ob0 = __shfl_xor(e0[qi], m), ob1 = __shfl_xor(e1[qi], m), ob2 = __shfl_xor(e2[qi], m);
            int   oj0 = __shfl_xor(i0[qi], m), oj1 = __shfl_xor(i1[qi], m), oj2 = __shfl_xor(i2[qi], m);
            float dv[3] = {ob0, ob1, ob2}; int iv[3] = {oj0, oj1, oj2};
#pragma unroll
            for (int e = 0; e < 3; ++e) {
                float d = dv[e]; int s = iv[e];
                bool lt2 = (d < e2[qi]) || (d == e2[qi] && s < i2[qi]);
                if (lt2) {
                    bool lt1 = (d < e1[qi]) || (d == e1[qi] && s < i1[qi]);
                    bool lt0 = (d < e0[qi]) || (d == e0[qi] && s < i0[qi]);
                    e2[qi] = lt1 ? e1[qi] : d;  i2[qi] = lt1 ? i1[qi] : s;
                    e1[qi] = lt0 ? e0[qi] : (lt1 ? d : e1[qi]);
                    i1[qi] = lt0 ? i0[qi] : (lt1 ? s : i1[qi]);
                    e0[qi] = lt0 ? d : e0[qi];  i0[qi] = lt0 ? s : i0[qi];
                }
            }
        }
    }

    if (l == 0) {
#pragma unroll
        for (int qi = 0; qi < 2; ++qi) {
            float nx = px[qi], ny = py[qi], nz = pz[qi];
            float n1 = nx*nx + ny*ny + nz*nz;
            float d0 = sqrtf(fmaxf(n1 + e0[qi], 0.f));
            float d1 = sqrtf(fmaxf(n1 + e1[qi], 0.f));
            float d2s = sqrtf(fmaxf(n1 + e2[qi], 0.f));
            float w0 = 1.f / fmaxf(d0, 1e-10f);
            float w1 = 1.f / fmaxf(d1, 1e-10f);
            float w2 = 1.f / fmaxf(d2s, 1e-10f);
            float wsum = w0 + w1 + w2;
            size_t qg = (size_t)b * NN + qa + qi;
            int*   np = (int*)(nnbuf + qg * 32);
            float* wp = (float*)(nnbuf + qg * 32 + 16);
            np[0] = b * SS + i0[qi];
            np[1] = b * SS + i1[qi];
            np[2] = b * SS + i2[qi];
            wp[0] = w0 / wsum; wp[1] = w1 / wsum; wp[2] = w2 / wsum;
        }
    }
}

// ---------------------------------------------------------------------------
// Both weight transposes (W1: 384x256, W2: 256x256) in one launch.
// ---------------------------------------------------------------------------
__global__ __launch_bounds__(256) void transpose_cvt_both_kernel(
    const float* __restrict__ W1, ushort* __restrict__ W1t,
    const float* __restrict__ W2, ushort* __restrict__ W2t)
{
    int idx = blockIdx.x * 256 + threadIdx.x;
    const int n1 = KIN * OUTC;                    // 98304
    if (idx < n1) {
        int n = idx / KIN, k = idx - n * KIN;
        W1t[idx] = f2bf(W1[(size_t)k * OUTC + n]);
    } else {
        int j = idx - n1;
        if (j < OUTC * OUTC) {
            int n = j / OUTC, k = j - n * OUTC;
            W2t[j] = f2bf(W2[(size_t)k * OUTC + n]);
        }
    }
}

// ---------------------------------------------------------------------------
// FUSED two-layer MFMA GEMM, v4 = r13 structure + FUSED 3-NN GATHER:
//   out = relu(relu([feat1|interp]@W1t^T + b1)@W2t^T + b2), H in LDS only.
// NEW: for interp K-steps (k0>=128) the A-staging reads (idx,w) from the
// 32B/query nn record and blends the 3 feat2 row-slices (f32, L2-resident)
// in registers -> bf16 -> ds_write at the identical swizzled LDS offsets.
// Kills the 33.5MB interp write + 33.5MB read vs r13. Blend VALU co-issues
// with the MFMA pipe. Identical blend expression to the old gather kernel.
// Phase-1 double-buffered in the H pool; phase 2 identical to r11/r13.
// LDS: 64KB pool + 16KB sB2 = 80KB -> 2 blocks/CU; VGPR capped 128 by
// __launch_bounds__(512,4) (spill = abort criterion).
// C/D mapping (verified r1+): col = lane&15, row = (lane>>4)*4 + reg.
// ---------------------------------------------------------------------------
#define GBM 128
#define GBN 256
#define GBK 32

__device__ __forceinline__ void gld_lds16(const void* g, void* l) {
    __builtin_amdgcn_global_load_lds(
        (const __attribute__((address_space(1))) void*)g,
        (__attribute__((address_space(3))) void*)l, 16, 0, 0);
}

__global__ __launch_bounds__(512, 4) void gemm_fused(
    const float* __restrict__ feat1,
    const float* __restrict__ feat2,
    const char* __restrict__ nnbuf,
    const ushort* __restrict__ W1t, const float* __restrict__ b1,
    const ushort* __restrict__ W2t, const float* __restrict__ b2,
    float* __restrict__ out)
{
    __shared__ ushort pool[GBM * 256];   // 64 KB: phase1 dbuf (2x24KB); then H
    __shared__ ushort sB2[GBN * GBK];    // 16 KB: phase2 W2t K-slice

    const int tid  = threadIdx.x;
    const int lane = tid & 63;
    const int wid  = tid >> 6;           // 0..7
    const int m0   = blockIdx.x * GBM;
    const int wr   = wid >> 2;           // 0..1
    const int wc   = wid & 3;            // 0..3

    const int rsub = lane >> 2;                    // 0..15 (row in 16-row chunk)
    const int slot = lane & 3;                     // 0..3  (8-ushort slot)
    const int csub = slot * 8;                     // linear LDS slot offset
    const int usw  = (slot ^ (rsub & 3)) * 8;      // swizzled SOURCE slot offset

    const int kgrp = (lane >> 4) * 8;
    const int rl   = lane & 15;
    const int ksw  = kgrp ^ ((rl & 3) << 3);       // swizzled read slot
    const int cl   = lane & 15;
    const int rgrp = (lane >> 4) * 4;

    // stage one K-step of A (8 chunks) + W1t (16 chunks) into buffer `buf`.
    // 24 chunks over 8 waves = 3 per wave, wave-uniform cid.
    auto stageAB = [&](int k0, int buf) {
        ushort* sAb = pool + buf * 12288;          // 8KB A
        ushort* sBb = sAb + 4096;                  // 16KB B
#pragma unroll
        for (int c = 0; c < 3; ++c) {
            const int cid = wid * 3 + c;           // 0..23
            if (cid < 8) {
                const int r = m0 + cid * 16 + rsub;
                if (k0 < C1C) {
                    const float* src = feat1 + (size_t)r * C1C + k0 + usw;
                    float4 u = ((const float4*)src)[0];
                    float4 v = ((const float4*)src)[1];
                    ushortx8 t;
                    t[0] = f2bf(u.x); t[1] = f2bf(u.y); t[2] = f2bf(u.z); t[3] = f2bf(u.w);
                    t[4] = f2bf(v.x); t[5] = f2bf(v.y); t[6] = f2bf(v.z); t[7] = f2bf(v.w);
                    *(ushortx8*)&sAb[cid * 512 + rsub * 32 + csub] = t;
                } else {
                    // fused 3-NN gather+blend from feat2 (L2-resident)
                    const char* nr = nnbuf + (size_t)r * 32;
                    const int4   iv = *(const int4*)nr;
                    const float4 wv = *(const float4*)(nr + 16);
                    const int kc = (k0 - C1C) + usw;
                    const float* p0 = feat2 + (size_t)iv.x * C2C + kc;
                    const float* p1 = feat2 + (size_t)iv.y * C2C + kc;
                    const float* p2 = feat2 + (size_t)iv.z * C2C + kc;
                    float4 a0 = ((const float4*)p0)[0];
                    float4 a1 = ((const float4*)p1)[0];
                    float4 a2 = ((const float4*)p2)[0];
                    ushortx8 t;
                    t[0] = f2bf(wv.x*a0.x + wv.y*a1.x + wv.z*a2.x);
                    t[1] = f2bf(wv.x*a0.y + wv.y*a1.y + wv.z*a2.y);
                    t[2] = f2bf(wv.x*a0.z + wv.y*a1.z + wv.z*a2.z);
                    t[3] = f2bf(wv.x*a0.w + wv.y*a1.w + wv.z*a2.w);
                    float4 b0 = ((const float4*)p0)[1];
                    float4 b1v = ((const float4*)p1)[1];
                    float4 b2v = ((const float4*)p2)[1];
                    t[4] = f2bf(wv.x*b0.x + wv.y*b1v.x + wv.z*b2v.x);
                    t[5] = f2bf(wv.x*b0.y + wv.y*b1v.y + wv.z*b2v.y);
                    t[6] = f2bf(wv.x*b0.z + wv.y*b1v.z + wv.z*b2v.z);
                    t[7] = f2bf(wv.x*b0.w + wv.y*b1v.w + wv.z*b2v.w);
                    *(ushortx8*)&sAb[cid * 512 + rsub * 32 + csub] = t;
                }
            } else {
                const int bi = cid - 8;
                const int r = bi * 16 + rsub;
                gld_lds16(W1t + (size_t)r * KIN + k0 + usw, &sBb[bi * 512]);
            }
        }
    };

    // ---------------- phase 1: acc1 = A @ W1t^T (double-buffered) ----------
    f32x4 acc1[4][4];
#pragma unroll
    for (int i = 0; i < 4; ++i)
#pragma unroll
        for (int j = 0; j < 4; ++j) acc1[i][j] = (f32x4){0.f, 0.f, 0.f, 0.f};

    int cur = 0;
    stageAB(0, 0);
    for (int k0 = 0; k0 < KIN; k0 += GBK) {
        __syncthreads();                 // stage(k0->cur) done; prev reads done
        if (k0 + GBK < KIN) stageAB(k0 + GBK, cur ^ 1);

        const ushort* sAb = pool + cur * 12288;
        const ushort* sBb = sAb + 4096;
        short8 af[4], bf[4];
#pragma unroll
        for (int i = 0; i < 4; ++i) {
            af[i] = *(const short8*)&sAb[(wr * 64 + i * 16 + rl) * GBK + ksw];
            bf[i] = *(const short8*)&sBb[(wc * 64 + i * 16 + rl) * GBK + ksw];
        }
#pragma unroll
        for (int i = 0; i < 4; ++i)
#pragma unroll
            for (int j = 0; j < 4; ++j)
                acc1[i][j] = __builtin_amdgcn_mfma_f32_16x16x32_bf16(
                    af[i], bf[j], acc1[i][j], 0, 0, 0);
        cur ^= 1;
    }
    __syncthreads();                     // all phase-1 LDS reads done (pool reuse)

    // ---------------- transition: H = relu(acc1+b1) -> LDS (bf16) ----------
    // stage first W2t K-slice while writing H (latency overlap)
#pragma unroll
    for (int c = 0; c < 2; ++c) {
        const int cid = wid * 2 + c;                   // 0..15
        const int r = cid * 16 + rsub;
        gld_lds16(W2t + (size_t)r * OUTC + 0 + usw, &sB2[cid * 512]);
    }

#pragma unroll
    for (int j = 0; j < 4; ++j) {
        const int c = wc * 64 + j * 16 + cl;
        const float bv = b1[c];
        const int u = c >> 3, sub = c & 7;
#pragma unroll
        for (int i = 0; i < 4; ++i) {
#pragma unroll
            for (int rr = 0; rr < 4; ++rr) {
                const int r = wr * 64 + i * 16 + rgrp + rr;
                const float v = fmaxf(acc1[i][j][rr] + bv, 0.f);
                pool[r * 256 + ((u ^ (r & 31)) << 3) + sub] = f2bf(v);
            }
        }
    }
    __syncthreads();   // H complete + sB2(k0=0) staged (vmcnt drained by barrier)

    // ---------------- phase 2: out = relu(H @ W2t^T + b2) ------------------
    f32x4 acc2[4][4];
#pragma unroll
    for (int i = 0; i < 4; ++i)
#pragma unroll
        for (int j = 0; j < 4; ++j) acc2[i][j] = (f32x4){0.f, 0.f, 0.f, 0.f};

    for (int k0 = 0; k0 < OUTC; k0 += GBK) {
        short8 af[4], bf[4];
        const int ub = (k0 >> 3) + (lane >> 4);        // H unit index 0..31
#pragma unroll
        for (int i = 0; i < 4; ++i) {
            const int r = wr * 64 + i * 16 + rl;
            af[i] = *(const short8*)&pool[r * 256 + ((ub ^ (r & 31)) << 3)];
            bf[i] = *(const short8*)&sB2[(wc * 64 + i * 16 + rl) * GBK + ksw];
        }
#pragma unroll
        for (int i = 0; i < 4; ++i)
#pragma unroll
            for (int j = 0; j < 4; ++j)
                acc2[i][j] = __builtin_amdgcn_mfma_f32_16x16x32_bf16(
                    af[i], bf[j], acc2[i][j], 0, 0, 0);

        const int kn = k0 + GBK;
        __syncthreads();                               // sB2 reads complete
        if (kn < OUTC) {
#pragma unroll
            for (int c = 0; c < 2; ++c) {
                const int cid = wid * 2 + c;
                const int r = cid * 16 + rsub;
                gld_lds16(W2t + (size_t)r * OUTC + kn + usw, &sB2[cid * 512]);
            }
            __syncthreads();
        }
    }

    // ---------------- epilogue: bias + relu -> f32 out ---------------------
#pragma unroll
    for (int j = 0; j < 4; ++j) {
        const int col = wc * 64 + j * 16 + cl;
        const float bv = b2[col];
#pragma unroll
        for (int i = 0; i < 4; ++i) {
            const int rowb = m0 + wr * 64 + i * 16 + rgrp;
#pragma unroll
            for (int rr = 0; rr < 4; ++rr) {
                out[(size_t)(rowb + rr) * OUTC + col] =
                    fmaxf(acc2[i][j][rr] + bv, 0.f);
            }
        }
    }
}

// ---------------------------------------------------------------------------
// ws layout (bytes): nn 2MB @0 | W1t @2097152 | W2t @2293760
// ---------------------------------------------------------------------------
extern "C" void kernel_launch(void* const* d_in, const int* in_sizes, int n_in,
                              void* d_out, int out_size, void* d_ws, size_t ws_size,
                              hipStream_t stream) {
    const float* xyz1  = (const float*)d_in[0];
    const float* xyz2  = (const float*)d_in[1];
    const float* feat1 = (const float*)d_in[2];
    const float* feat2 = (const float*)d_in[3];
    const float* W1    = (const float*)d_in[4];
    const float* b1    = (const float*)d_in[5];
    const float* W2    = (const float*)d_in[6];
    const float* b2    = (const float*)d_in[7];
    float* out = (float*)d_out;

    char* ws = (char*)d_ws;
    char*   nnbuf = ws;                            // 65536 * 32B = 2 MB
    ushort* W1t   = (ushort*)(ws + 2097152);
    ushort* W2t   = (ushort*)(ws + 2293760);

    const int M = BB * NN;  // 65536

    transpose_cvt_both_kernel<<<(KIN * OUTC + OUTC * OUTC + 255) / 256, 256, 0, stream>>>(
        W1, W1t, W2, W2t);

    knn_kernel<<<512, 1024, 0, stream>>>(xyz1, xyz2, nnbuf);

    gemm_fused<<<M / GBM, 512, 0, stream>>>(feat1, feat2, nnbuf,
                                            W1t, b1, W2t, b2, out);
}

// Round 15
// 117.557 us; speedup vs baseline: 1.0297x; 1.0297x over previous
//
#include <hip/hip_runtime.h>
#include <hip/hip_bf16.h>

// Problem constants: B=8, N=8192, S=2048, C1=128, C2=256, OUT=256
#define BB   8
#define NN   8192
#define SS   2048
#define C1C  128
#define C2C  256
#define KIN  384
#define OUTC 256

typedef __attribute__((ext_vector_type(4))) float f32x4;
typedef __attribute__((ext_vector_type(8))) short short8;
typedef __attribute__((ext_vector_type(8))) unsigned short ushortx8;

__device__ __forceinline__ ushort f2bf(float v) {
    __hip_bfloat16 h = __float2bfloat16(v);
    return __builtin_bit_cast(ushort, h);
}

__device__ __forceinline__ float med3(float a, float b, float c) {
    return __builtin_amdgcn_fmed3f(a, b, c);
}

// ---------------------------------------------------------------------------
// Fused 3-NN scan + gather (r13-measured 65.5us structure) + NEW prologue:
// feat1 f32 -> bf16 conversion for this block's 128 query rows (coalesced,
// hidden under the VALU-bound scan; knn runs at 8% HBM). gemm then stages
// A entirely as bf16 via global_load_lds (r14's in-staging gather reverted:
// scattered loads on the barrier path were latency-poison).
// L=16 lanes/query, Q=2 queries/thread, 128 queries/block, 1024 threads,
// grid 512 = 2 blocks/CU = 8 waves/SIMD. Two-pass: branchless med3 value
// pass -> exact 3rd-smallest threshold -> rare-insert index pass (lex
// (f,idx) == stable lax.top_k). Gather: coalesced 1KB feat2 rows -> interpB.
// ---------------------------------------------------------------------------
__global__ __launch_bounds__(1024, 8) void knn_gather_kernel(
    const float* __restrict__ xyz1, const float* __restrict__ xyz2,
    const float* __restrict__ feat2, const float* __restrict__ feat1,
    ushort* __restrict__ feat1B, ushort* __restrict__ interpB)
{
    __shared__ float4 sp[SS];                     // 32 KB
    __shared__ int   sIdx[128][3];
    __shared__ float sW[128][3];

    const int tid   = threadIdx.x;
    const int b     = blockIdx.x & 7;             // XCD-aligned batch
    const int chunk = blockIdx.x >> 3;            // 0..63
    const int qbase = chunk << 7;                 // 128 queries per block

    // -------- prologue: feat1 f32 -> bf16 for this block's 128 rows --------
    // 8 threads/row, 16 floats each; loads overlap sp staging + scan.
    {
        const int qq = tid >> 3, part = tid & 7;
        const size_t row = (size_t)b * NN + qbase + qq;
        const float4* src = (const float4*)(feat1 + row * C1C + part * 16);
        float4 u0 = src[0], u1 = src[1], u2 = src[2], u3 = src[3];
        ushortx8 t0, t1;
        t0[0] = f2bf(u0.x); t0[1] = f2bf(u0.y); t0[2] = f2bf(u0.z); t0[3] = f2bf(u0.w);
        t0[4] = f2bf(u1.x); t0[5] = f2bf(u1.y); t0[6] = f2bf(u1.z); t0[7] = f2bf(u1.w);
        t1[0] = f2bf(u2.x); t1[1] = f2bf(u2.y); t1[2] = f2bf(u2.z); t1[3] = f2bf(u2.w);
        t1[4] = f2bf(u3.x); t1[5] = f2bf(u3.y); t1[6] = f2bf(u3.z); t1[7] = f2bf(u3.w);
        ushortx8* dst = (ushortx8*)(feat1B + row * C1C + part * 16);
        dst[0] = t0; dst[1] = t1;
    }

    const float* x2 = xyz2 + (size_t)b * SS * 3;
    for (int i = tid; i < SS; i += 1024) {
        float x = x2[i*3+0], y = x2[i*3+1], z = x2[i*3+2];
        sp[i] = make_float4(-2.f*x, -2.f*y, -2.f*z, x*x + y*y + z*z);
    }
    __syncthreads();

    const int g = tid >> 4;                       // 0..63 (query pair)
    const int l = tid & 15;                       // lane within query
    const int qa = qbase + g * 2;

    const float* qp = xyz1 + ((size_t)b * NN + qa) * 3;
    float px[2] = {qp[0], qp[3]};
    float py[2] = {qp[1], qp[4]};
    float pz[2] = {qp[2], qp[5]};

    // ---------------- pass 1: top-3 values, branchless ----------------
    float c0[2], c1[2], c2[2];
#pragma unroll
    for (int qi = 0; qi < 2; ++qi) { c0[qi] = c1[qi] = c2[qi] = 1e30f; }

    for (int jj = 0; jj < 128; jj += 4) {
        float4 P[4];
#pragma unroll
        for (int u = 0; u < 4; ++u) P[u] = sp[((jj + u) << 4) + l];
#pragma unroll
        for (int u = 0; u < 4; ++u) {
#pragma unroll
            for (int qi = 0; qi < 2; ++qi) {
                float f = fmaf(px[qi], P[u].x,
                          fmaf(py[qi], P[u].y,
                          fmaf(pz[qi], P[u].z, P[u].w)));
                c2[qi] = med3(f, c1[qi], c2[qi]);
                c1[qi] = med3(f, c0[qi], c1[qi]);
                c0[qi] = fminf(f, c0[qi]);
            }
        }
    }

    // value-merge across the 16-lane group (multiset union top-3)
#pragma unroll
    for (int m = 1; m <= 8; m <<= 1) {
#pragma unroll
        for (int qi = 0; qi < 2; ++qi) {
            float b0 = __shfl_xor(c0[qi], m);
            float b1 = __shfl_xor(c1[qi], m);
            float b2 = __shfl_xor(c2[qi], m);
            float bv[3] = {b0, b1, b2};
#pragma unroll
            for (int e = 0; e < 3; ++e) {
                float d = bv[e];
                c2[qi] = med3(d, c1[qi], c2[qi]);
                c1[qi] = med3(d, c0[qi], c1[qi]);
                c0[qi] = fminf(d, c0[qi]);
            }
        }
    }
    const float t0 = c2[0], t1 = c2[1];           // exact 3rd-smallest scores

    // ---------------- pass 2: index recovery (rare inserts) ----------------
    float e0[2], e1[2], e2[2];
    int   i0[2], i1[2], i2[2];
#pragma unroll
    for (int qi = 0; qi < 2; ++qi) {
        e0[qi] = e1[qi] = e2[qi] = 1e30f;
        i0[qi] = i1[qi] = i2[qi] = 0x3fffffff;
    }

    for (int jj = 0; jj < 128; jj += 4) {
        float4 P[4];
#pragma unroll
        for (int u = 0; u < 4; ++u) P[u] = sp[((jj + u) << 4) + l];
#pragma unroll
        for (int u = 0; u < 4; ++u) {
            const int s = ((jj + u) << 4) + l;
#pragma unroll
            for (int qi = 0; qi < 2; ++qi) {
                float f = fmaf(px[qi], P[u].x,
                          fmaf(py[qi], P[u].y,
                          fmaf(pz[qi], P[u].z, P[u].w)));
                float tq = qi ? t1 : t0;
                if (f <= tq) {                     // ~3 hits per query total
                    bool lt2 = (f < e2[qi]) || (f == e2[qi] && s < i2[qi]);
                    if (lt2) {
                        bool lt1 = (f < e1[qi]) || (f == e1[qi] && s < i1[qi]);
                        bool lt0 = (f < e0[qi]) || (f == e0[qi] && s < i0[qi]);
                        e2[qi] = lt1 ? e1[qi] : f;  i2[qi] = lt1 ? i1[qi] : s;
                        e1[qi] = lt0 ? e0[qi] : (lt1 ? f : e1[qi]);
                        i1[qi] = lt0 ? i0[qi] : (lt1 ? s : i1[qi]);
                        e0[qi] = lt0 ? f : e0[qi];  i0[qi] = lt0 ? s : i0[qi];
                    }
                }
            }
        }
    }

    // lex merge across the 16-lane group
#pragma unroll
    for (int m = 1; m <= 8; m <<= 1) {
#pragma unroll
        for (int qi = 0; qi < 2; ++qi) {
            float ob0 = __shfl_xor(e0[qi], m), ob1 = __shfl_xor(e1[qi], m), ob2 = __shfl_xor(e2[qi], m);
            int   oj0 = __shfl_xor(i0[qi], m), oj1 = __shfl_xor(i1[qi], m), oj2 = __shfl_xor(i2[qi], m);
            float dv[3] = {ob0, ob1, ob2}; int iv[3] = {oj0, oj1, oj2};
#pragma unroll
            for (int e = 0; e < 3; ++e) {
                float d = dv[e]; int s = iv[e];
                bool lt2 = (d < e2[qi]) || (d == e2[qi] && s < i2[qi]);
                if (lt2) {
                    bool lt1 = (d < e1[qi]) || (d == e1[qi] && s < i1[qi]);
                    bool lt0 = (d < e0[qi]) || (d == e0[qi] && s < i0[qi]);
                    e2[qi] = lt1 ? e1[qi] : d;  i2[qi] = lt1 ? i1[qi] : s;
                    e1[qi] = lt0 ? e0[qi] : (lt1 ? d : e1[qi]);
                    i1[qi] = lt0 ? i0[qi] : (lt1 ? s : i1[qi]);
                    e0[qi] = lt0 ? d : e0[qi];  i0[qi] = lt0 ? s : i0[qi];
                }
            }
        }
    }

    if (l == 0) {
#pragma unroll
        for (int qi = 0; qi < 2; ++qi) {
            float nx = px[qi], ny = py[qi], nz = pz[qi];
            float n1 = nx*nx + ny*ny + nz*nz;
            float d0 = sqrtf(fmaxf(n1 + e0[qi], 0.f));
            float d1 = sqrtf(fmaxf(n1 + e1[qi], 0.f));
            float d2s = sqrtf(fmaxf(n1 + e2[qi], 0.f));
            float w0 = 1.f / fmaxf(d0, 1e-10f);
            float w1 = 1.f / fmaxf(d1, 1e-10f);
            float w2 = 1.f / fmaxf(d2s, 1e-10f);
            float wsum = w0 + w1 + w2;
            int qq = g * 2 + qi;
            sIdx[qq][0] = i0[qi]; sIdx[qq][1] = i1[qi]; sIdx[qq][2] = i2[qi];
            sW[qq][0] = w0 / wsum; sW[qq][1] = w1 / wsum; sW[qq][2] = w2 / wsum;
        }
    }
    __syncthreads();

    // gather phase: wave wid handles queries wid, wid+16, ... (coalesced rows)
    const int wid = tid >> 6, lane = tid & 63;
    for (int qq = wid; qq < 128; qq += 16) {
        int a0 = sIdx[qq][0], a1 = sIdx[qq][1], a2 = sIdx[qq][2];
        float w0 = sW[qq][0], w1 = sW[qq][1], w2 = sW[qq][2];
        const float4* r0 = (const float4*)(feat2 + ((size_t)b * SS + a0) * C2C);
        const float4* r1 = (const float4*)(feat2 + ((size_t)b * SS + a1) * C2C);
        const float4* r2 = (const float4*)(feat2 + ((size_t)b * SS + a2) * C2C);
        float4 v0 = r0[lane], v1 = r1[lane], v2 = r2[lane];
        ushort4 o;
        o.x = f2bf(w0*v0.x + w1*v1.x + w2*v2.x);
        o.y = f2bf(w0*v0.y + w1*v1.y + w2*v2.y);
        o.z = f2bf(w0*v0.z + w1*v1.z + w2*v2.z);
        o.w = f2bf(w0*v0.w + w1*v1.w + w2*v2.w);
        *(ushort4*)(interpB + ((size_t)b * NN + qbase + qq) * C2C + lane * 4) = o;
    }
}

// ---------------------------------------------------------------------------
// Both weight transposes (W1: 384x256, W2: 256x256) in one launch.
// ---------------------------------------------------------------------------
__global__ __launch_bounds__(256) void transpose_cvt_both_kernel(
    const float* __restrict__ W1, ushort* __restrict__ W1t,
    const float* __restrict__ W2, ushort* __restrict__ W2t)
{
    int idx = blockIdx.x * 256 + threadIdx.x;
    const int n1 = KIN * OUTC;                    // 98304
    if (idx < n1) {
        int n = idx / KIN, k = idx - n * KIN;
        W1t[idx] = f2bf(W1[(size_t)k * OUTC + n]);
    } else {
        int j = idx - n1;
        if (j < OUTC * OUTC) {
            int n = j / OUTC, k = j - n * OUTC;
            W2t[j] = f2bf(W2[(size_t)k * OUTC + n]);
        }
    }
}

// ---------------------------------------------------------------------------
// FUSED two-layer MFMA GEMM (r13 structure; A now all-bf16):
//   out = relu(relu([feat1B|interpB]@W1t^T + b1)@W2t^T + b2), H in LDS only.
// r14 lesson: scattered gather loads inside staging are latency-poison ->
// interp stays materialized by knn. feat1 is pre-converted to bf16 (knn
// prologue) so ALL A-staging is uniform global_load_lds (no f32 path).
// Phase-1 double-buffered in the H pool (1 barrier/K-step); phase 2 with
// sB2-staged W2t (r11/r13-measured-good).
// LDS: 64KB pool + 16KB sB2 = 80KB -> 2 blocks/CU.
// C/D mapping (verified r1+): col = lane&15, row = (lane>>4)*4 + reg.
// ---------------------------------------------------------------------------
#define GBM 128
#define GBN 256
#define GBK 32

__device__ __forceinline__ void gld_lds16(const void* g, void* l) {
    __builtin_amdgcn_global_load_lds(
        (const __attribute__((address_space(1))) void*)g,
        (__attribute__((address_space(3))) void*)l, 16, 0, 0);
}

__global__ __launch_bounds__(512, 4) void gemm_fused(
    const ushort* __restrict__ feat1B,
    const ushort* __restrict__ interpB,
    const ushort* __restrict__ W1t, const float* __restrict__ b1,
    const ushort* __restrict__ W2t, const float* __restrict__ b2,
    float* __restrict__ out)
{
    __shared__ ushort pool[GBM * 256];   // 64 KB: phase1 dbuf (2x24KB); then H
    __shared__ ushort sB2[GBN * GBK];    // 16 KB: phase2 W2t K-slice

    const int tid  = threadIdx.x;
    const int lane = tid & 63;
    const int wid  = tid >> 6;           // 0..7
    const int m0   = blockIdx.x * GBM;
    const int wr   = wid >> 2;           // 0..1
    const int wc   = wid & 3;            // 0..3

    const int rsub = lane >> 2;                    // 0..15 (row in 16-row chunk)
    const int slot = lane & 3;                     // 0..3  (8-ushort slot)
    const int usw  = (slot ^ (rsub & 3)) * 8;      // swizzled SOURCE slot offset

    const int kgrp = (lane >> 4) * 8;
    const int rl   = lane & 15;
    const int ksw  = kgrp ^ ((rl & 3) << 3);       // swizzled read slot
    const int cl   = lane & 15;
    const int rgrp = (lane >> 4) * 4;

    // stage one K-step of A (8 chunks) + W1t (16 chunks) into buffer `buf`.
    // 24 chunks over 8 waves = 3 per wave, wave-uniform cid; all gld_lds16.
    auto stageAB = [&](int k0, int buf) {
        ushort* sAb = pool + buf * 12288;          // 8KB A
        ushort* sBb = sAb + 4096;                  // 16KB B
#pragma unroll
        for (int c = 0; c < 3; ++c) {
            const int cid = wid * 3 + c;           // 0..23
            if (cid < 8) {
                const int r = m0 + cid * 16 + rsub;
                const ushort* src = (k0 < C1C)
                    ? (feat1B + (size_t)r * C1C + k0 + usw)
                    : (interpB + (size_t)r * C2C + (k0 - C1C) + usw);
                gld_lds16(src, &sAb[cid * 512]);
            } else {
                const int bi = cid - 8;
                const int r = bi * 16 + rsub;
                gld_lds16(W1t + (size_t)r * KIN + k0 + usw, &sBb[bi * 512]);
            }
        }
    };

    // ---------------- phase 1: acc1 = A @ W1t^T (double-buffered) ----------
    f32x4 acc1[4][4];
#pragma unroll
    for (int i = 0; i < 4; ++i)
#pragma unroll
        for (int j = 0; j < 4; ++j) acc1[i][j] = (f32x4){0.f, 0.f, 0.f, 0.f};

    int cur = 0;
    stageAB(0, 0);
    for (int k0 = 0; k0 < KIN; k0 += GBK) {
        __syncthreads();                 // stage(k0->cur) done; prev reads done
        if (k0 + GBK < KIN) stageAB(k0 + GBK, cur ^ 1);

        const ushort* sAb = pool + cur * 12288;
        const ushort* sBb = sAb + 4096;
        short8 af[4], bf[4];
#pragma unroll
        for (int i = 0; i < 4; ++i) {
            af[i] = *(const short8*)&sAb[(wr * 64 + i * 16 + rl) * GBK + ksw];
            bf[i] = *(const short8*)&sBb[(wc * 64 + i * 16 + rl) * GBK + ksw];
        }
#pragma unroll
        for (int i = 0; i < 4; ++i)
#pragma unroll
            for (int j = 0; j < 4; ++j)
                acc1[i][j] = __builtin_amdgcn_mfma_f32_16x16x32_bf16(
                    af[i], bf[j], acc1[i][j], 0, 0, 0);
        cur ^= 1;
    }
    __syncthreads();                     // all phase-1 LDS reads done (pool reuse)

    // ---------------- transition: H = relu(acc1+b1) -> LDS (bf16) ----------
    // stage first W2t K-slice while writing H (latency overlap)
#pragma unroll
    for (int c = 0; c < 2; ++c) {
        const int cid = wid * 2 + c;                   // 0..15
        const int r = cid * 16 + rsub;
        gld_lds16(W2t + (size_t)r * OUTC + 0 + usw, &sB2[cid * 512]);
    }

#pragma unroll
    for (int j = 0; j < 4; ++j) {
        const int c = wc * 64 + j * 16 + cl;
        const float bv = b1[c];
        const int u = c >> 3, sub = c & 7;
#pragma unroll
        for (int i = 0; i < 4; ++i) {
#pragma unroll
            for (int rr = 0; rr < 4; ++rr) {
                const int r = wr * 64 + i * 16 + rgrp + rr;
                const float v = fmaxf(acc1[i][j][rr] + bv, 0.f);
                pool[r * 256 + ((u ^ (r & 31)) << 3) + sub] = f2bf(v);
            }
        }
    }
    __syncthreads();   // H complete + sB2(k0=0) staged (vmcnt drained by barrier)

    // ---------------- phase 2: out = relu(H @ W2t^T + b2) ------------------
    f32x4 acc2[4][4];
#pragma unroll
    for (int i = 0; i < 4; ++i)
#pragma unroll
        for (int j = 0; j < 4; ++j) acc2[i][j] = (f32x4){0.f, 0.f, 0.f, 0.f};

    for (int k0 = 0; k0 < OUTC; k0 += GBK) {
        short8 af[4], bf[4];
        const int ub = (k0 >> 3) + (lane >> 4);        // H unit index 0..31
#pragma unroll
        for (int i = 0; i < 4; ++i) {
            const int r = wr * 64 + i * 16 + rl;
            af[i] = *(const short8*)&pool[r * 256 + ((ub ^ (r & 31)) << 3)];
            bf[i] = *(const short8*)&sB2[(wc * 64 + i * 16 + rl) * GBK + ksw];
        }
#pragma unroll
        for (int i = 0; i < 4; ++i)
#pragma unroll
            for (int j = 0; j < 4; ++j)
                acc2[i][j] = __builtin_amdgcn_mfma_f32_16x16x32_bf16(
                    af[i], bf[j], acc2[i][j], 0, 0, 0);

        const int kn = k0 + GBK;
        __syncthreads();                               // sB2 reads complete
        if (kn < OUTC) {
#pragma unroll
            for (int c = 0; c < 2; ++c) {
                const int cid = wid * 2 + c;
                const int r = cid * 16 + rsub;
                gld_lds16(W2t + (size_t)r * OUTC + kn + usw, &sB2[cid * 512]);
            }
            __syncthreads();
        }
    }

    // ---------------- epilogue: bias + relu -> f32 out ---------------------
#pragma unroll
    for (int j = 0; j < 4; ++j) {
        const int col = wc * 64 + j * 16 + cl;
        const float bv = b2[col];
#pragma unroll
        for (int i = 0; i < 4; ++i) {
            const int rowb = m0 + wr * 64 + i * 16 + rgrp;
#pragma unroll
            for (int rr = 0; rr < 4; ++rr) {
                out[(size_t)(rowb + rr) * OUTC + col] =
                    fmaxf(acc2[i][j][rr] + bv, 0.f);
            }
        }
    }
}

// ---------------------------------------------------------------------------
// ws layout (bytes): feat1B 16.8M @0 | interpB 33.5M @16777216
// | W1t @50331648 | W2t @50528256
// ---------------------------------------------------------------------------
extern "C" void kernel_launch(void* const* d_in, const int* in_sizes, int n_in,
                              void* d_out, int out_size, void* d_ws, size_t ws_size,
                              hipStream_t stream) {
    const float* xyz1  = (const float*)d_in[0];
    const float* xyz2  = (const float*)d_in[1];
    const float* feat1 = (const float*)d_in[2];
    const float* feat2 = (const float*)d_in[3];
    const float* W1    = (const float*)d_in[4];
    const float* b1    = (const float*)d_in[5];
    const float* W2    = (const float*)d_in[6];
    const float* b2    = (const float*)d_in[7];
    float* out = (float*)d_out;

    char* ws = (char*)d_ws;
    ushort* feat1B  = (ushort*)(ws);
    ushort* interpB = (ushort*)(ws + 16777216);
    ushort* W1t     = (ushort*)(ws + 50331648);
    ushort* W2t     = (ushort*)(ws + 50528256);

    const int M = BB * NN;  // 65536

    transpose_cvt_both_kernel<<<(KIN * OUTC + OUTC * OUTC + 255) / 256, 256, 0, stream>>>(
        W1, W1t, W2, W2t);

    knn_gather_kernel<<<512, 1024, 0, stream>>>(xyz1, xyz2, feat2, feat1,
                                                feat1B, interpB);

    gemm_fused<<<M / GBM, 512, 0, stream>>>(feat1B, interpB,
                                            W1t, b1, W2t, b2, out);
}

// Round 16
// 104.612 us; speedup vs baseline: 1.1571x; 1.1237x over previous
//
#include <hip/hip_runtime.h>
#include <hip/hip_bf16.h>

// Problem constants: B=8, N=8192, S=2048, C1=128, C2=256, OUT=256
#define BB   8
#define NN   8192
#define SS   2048
#define C1C  128
#define C2C  256
#define KIN  384
#define OUTC 256

typedef __attribute__((ext_vector_type(4))) float f32x4;
typedef __attribute__((ext_vector_type(8))) short short8;
typedef __attribute__((ext_vector_type(8))) unsigned short ushortx8;

__device__ __forceinline__ ushort f2bf(float v) {
    __hip_bfloat16 h = __float2bfloat16(v);
    return __builtin_bit_cast(ushort, h);
}

__device__ __forceinline__ float med3(float a, float b, float c) {
    return __builtin_amdgcn_fmed3f(a, b, c);
}

// ---------------------------------------------------------------------------
// Fused 3-NN scan + gather — EXACT r13 kernel (measured 65.5us; r15's feat1
// cvt prologue reverted: it delayed the scan start and cost +9.5us).
// L=16 lanes/query, Q=2 queries/thread, 128 queries/block, 1024 threads,
// grid 512 = 2 blocks/CU = 8 waves/SIMD. Two-pass: branchless med3 value
// pass -> exact 3rd-smallest threshold -> rare-insert index pass (lex
// (f,idx) == stable lax.top_k). Gather fused, coalesced 1KB feat2 rows.
// ---------------------------------------------------------------------------
__global__ __launch_bounds__(1024, 8) void knn_gather_kernel(
    const float* __restrict__ xyz1, const float* __restrict__ xyz2,
    const float* __restrict__ feat2, ushort* __restrict__ interpB)
{
    __shared__ float4 sp[SS];                     // 32 KB
    __shared__ int   sIdx[128][3];
    __shared__ float sW[128][3];

    const int tid   = threadIdx.x;
    const int b     = blockIdx.x & 7;             // XCD-aligned batch
    const int chunk = blockIdx.x >> 3;            // 0..63
    const int qbase = chunk << 7;                 // 128 queries per block

    const float* x2 = xyz2 + (size_t)b * SS * 3;
    for (int i = tid; i < SS; i += 1024) {
        float x = x2[i*3+0], y = x2[i*3+1], z = x2[i*3+2];
        sp[i] = make_float4(-2.f*x, -2.f*y, -2.f*z, x*x + y*y + z*z);
    }
    __syncthreads();

    const int g = tid >> 4;                       // 0..63 (query pair)
    const int l = tid & 15;                       // lane within query
    const int qa = qbase + g * 2;

    const float* qp = xyz1 + ((size_t)b * NN + qa) * 3;
    float px[2] = {qp[0], qp[3]};
    float py[2] = {qp[1], qp[4]};
    float pz[2] = {qp[2], qp[5]};

    // ---------------- pass 1: top-3 values, branchless ----------------
    float c0[2], c1[2], c2[2];
#pragma unroll
    for (int qi = 0; qi < 2; ++qi) { c0[qi] = c1[qi] = c2[qi] = 1e30f; }

    for (int jj = 0; jj < 128; jj += 4) {
        float4 P[4];
#pragma unroll
        for (int u = 0; u < 4; ++u) P[u] = sp[((jj + u) << 4) + l];
#pragma unroll
        for (int u = 0; u < 4; ++u) {
#pragma unroll
            for (int qi = 0; qi < 2; ++qi) {
                float f = fmaf(px[qi], P[u].x,
                          fmaf(py[qi], P[u].y,
                          fmaf(pz[qi], P[u].z, P[u].w)));
                c2[qi] = med3(f, c1[qi], c2[qi]);
                c1[qi] = med3(f, c0[qi], c1[qi]);
                c0[qi] = fminf(f, c0[qi]);
            }
        }
    }

    // value-merge across the 16-lane group (multiset union top-3)
#pragma unroll
    for (int m = 1; m <= 8; m <<= 1) {
#pragma unroll
        for (int qi = 0; qi < 2; ++qi) {
            float b0 = __shfl_xor(c0[qi], m);
            float b1 = __shfl_xor(c1[qi], m);
            float b2 = __shfl_xor(c2[qi], m);
            float bv[3] = {b0, b1, b2};
#pragma unroll
            for (int e = 0; e < 3; ++e) {
                float d = bv[e];
                c2[qi] = med3(d, c1[qi], c2[qi]);
                c1[qi] = med3(d, c0[qi], c1[qi]);
                c0[qi] = fminf(d, c0[qi]);
            }
        }
    }
    const float t0 = c2[0], t1 = c2[1];           // exact 3rd-smallest scores

    // ---------------- pass 2: index recovery (rare inserts) ----------------
    float e0[2], e1[2], e2[2];
    int   i0[2], i1[2], i2[2];
#pragma unroll
    for (int qi = 0; qi < 2; ++qi) {
        e0[qi] = e1[qi] = e2[qi] = 1e30f;
        i0[qi] = i1[qi] = i2[qi] = 0x3fffffff;
    }

    for (int jj = 0; jj < 128; jj += 4) {
        float4 P[4];
#pragma unroll
        for (int u = 0; u < 4; ++u) P[u] = sp[((jj + u) << 4) + l];
#pragma unroll
        for (int u = 0; u < 4; ++u) {
            const int s = ((jj + u) << 4) + l;
#pragma unroll
            for (int qi = 0; qi < 2; ++qi) {
                float f = fmaf(px[qi], P[u].x,
                          fmaf(py[qi], P[u].y,
                          fmaf(pz[qi], P[u].z, P[u].w)));
                float tq = qi ? t1 : t0;
                if (f <= tq) {                     // ~3 hits per query total
                    bool lt2 = (f < e2[qi]) || (f == e2[qi] && s < i2[qi]);
                    if (lt2) {
                        bool lt1 = (f < e1[qi]) || (f == e1[qi] && s < i1[qi]);
                        bool lt0 = (f < e0[qi]) || (f == e0[qi] && s < i0[qi]);
                        e2[qi] = lt1 ? e1[qi] : f;  i2[qi] = lt1 ? i1[qi] : s;
                        e1[qi] = lt0 ? e0[qi] : (lt1 ? f : e1[qi]);
                        i1[qi] = lt0 ? i0[qi] : (lt1 ? s : i1[qi]);
                        e0[qi] = lt0 ? f : e0[qi];  i0[qi] = lt0 ? s : i0[qi];
                    }
                }
            }
        }
    }

    // lex merge across the 16-lane group
#pragma unroll
    for (int m = 1; m <= 8; m <<= 1) {
#pragma unroll
        for (int qi = 0; qi < 2; ++qi) {
            float ob0 = __shfl_xor(e0[qi], m), ob1 = __shfl_xor(e1[qi], m), ob2 = __shfl_xor(e2[qi], m);
            int   oj0 = __shfl_xor(i0[qi], m), oj1 = __shfl_xor(i1[qi], m), oj2 = __shfl_xor(i2[qi], m);
            float dv[3] = {ob0, ob1, ob2}; int iv[3] = {oj0, oj1, oj2};
#pragma unroll
            for (int e = 0; e < 3; ++e) {
                float d = dv[e]; int s = iv[e];
                bool lt2 = (d < e2[qi]) || (d == e2[qi] && s < i2[qi]);
                if (lt2) {
                    bool lt1 = (d < e1[qi]) || (d == e1[qi] && s < i1[qi]);
                    bool lt0 = (d < e0[qi]) || (d == e0[qi] && s < i0[qi]);
                    e2[qi] = lt1 ? e1[qi] : d;  i2[qi] = lt1 ? i1[qi] : s;
                    e1[qi] = lt0 ? e0[qi] : (lt1 ? d : e1[qi]);
                    i1[qi] = lt0 ? i0[qi] : (lt1 ? s : i1[qi]);
                    e0[qi] = lt0 ? d : e0[qi];  i0[qi] = lt0 ? s : i0[qi];
                }
            }
        }
    }

    if (l == 0) {
#pragma unroll
        for (int qi = 0; qi < 2; ++qi) {
            float nx = px[qi], ny = py[qi], nz = pz[qi];
            float n1 = nx*nx + ny*ny + nz*nz;
            float d0 = sqrtf(fmaxf(n1 + e0[qi], 0.f));
            float d1 = sqrtf(fmaxf(n1 + e1[qi], 0.f));
            float d2s = sqrtf(fmaxf(n1 + e2[qi], 0.f));
            float w0 = 1.f / fmaxf(d0, 1e-10f);
            float w1 = 1.f / fmaxf(d1, 1e-10f);
            float w2 = 1.f / fmaxf(d2s, 1e-10f);
            float wsum = w0 + w1 + w2;
            int qq = g * 2 + qi;
            sIdx[qq][0] = i0[qi]; sIdx[qq][1] = i1[qi]; sIdx[qq][2] = i2[qi];
            sW[qq][0] = w0 / wsum; sW[qq][1] = w1 / wsum; sW[qq][2] = w2 / wsum;
        }
    }
    __syncthreads();

    // gather phase: wave wid handles queries wid, wid+16, ... (coalesced rows)
    const int wid = tid >> 6, lane = tid & 63;
    for (int qq = wid; qq < 128; qq += 16) {
        int a0 = sIdx[qq][0], a1 = sIdx[qq][1], a2 = sIdx[qq][2];
        float w0 = sW[qq][0], w1 = sW[qq][1], w2 = sW[qq][2];
        const float4* r0 = (const float4*)(feat2 + ((size_t)b * SS + a0) * C2C);
        const float4* r1 = (const float4*)(feat2 + ((size_t)b * SS + a1) * C2C);
        const float4* r2 = (const float4*)(feat2 + ((size_t)b * SS + a2) * C2C);
        float4 v0 = r0[lane], v1 = r1[lane], v2 = r2[lane];
        ushort4 o;
        o.x = f2bf(w0*v0.x + w1*v1.x + w2*v2.x);
        o.y = f2bf(w0*v0.y + w1*v1.y + w2*v2.y);
        o.z = f2bf(w0*v0.z + w1*v1.z + w2*v2.z);
        o.w = f2bf(w0*v0.w + w1*v1.w + w2*v2.w);
        *(ushort4*)(interpB + ((size_t)b * NN + qbase + qq) * C2C + lane * 4) = o;
    }
}

// ---------------------------------------------------------------------------
// Weight prep: W1t (N-major transpose, as before) + W2pack (fragment-packed
// for register-direct phase-2 B: W2pack[s][wc][j][lane][8] so each wave's
// bf-frag load is one contiguous 1KB burst).
//   o = global index into W2pack (65536 ushorts):
//   e=o&7; lane=(o>>3)&63; j=(o>>9)&3; wc=(o>>11)&3; s=o>>13;
//   n = wc*64 + j*16 + (lane&15); k = s*32 + (lane>>4)*8 + e;
//   W2pack[o] = bf16(W2[k][n])
// ---------------------------------------------------------------------------
__global__ __launch_bounds__(256) void weights_prep_kernel(
    const float* __restrict__ W1, ushort* __restrict__ W1t,
    const float* __restrict__ W2, ushort* __restrict__ W2pack)
{
    int idx = blockIdx.x * 256 + threadIdx.x;
    const int n1 = KIN * OUTC;                    // 98304
    if (idx < n1) {
        int n = idx / KIN, k = idx - n * KIN;
        W1t[idx] = f2bf(W1[(size_t)k * OUTC + n]);
    } else {
        int o = idx - n1;
        if (o < OUTC * OUTC) {
            int e = o & 7, lane = (o >> 3) & 63, j = (o >> 9) & 3;
            int wc = (o >> 11) & 3, s = o >> 13;
            int n = wc * 64 + j * 16 + (lane & 15);
            int k = s * 32 + (lane >> 4) * 8 + e;
            W2pack[o] = f2bf(W2[(size_t)k * OUTC + n]);
        }
    }
}

// ---------------------------------------------------------------------------
// FUSED two-layer MFMA GEMM, v5 = r13 phase 1 + register-B phase 2:
//   out = relu(relu([feat1|interpB]@W1^T + b1)@W2^T + b2), H in LDS only.
// Phase 1: EXACT r13 (dbuf staged A+W1t, 1 barrier/K-step, measured-good).
// Phase 2 (NEW): B-frags loaded straight from W2pack (contiguous 1KB L2
// bursts, one-step register prefetch) -> sB2 + its 16 barriers GONE;
// phase 2 is barrier-free after the transition; LDS reads halve (af only).
// This is r12's idea done right: r12 failed because frag loads were
// 768B-strided scatter; W2pack makes them coalesced streams.
// LDS: 64KB pool only -> 2 blocks/CU. VGPR target <=128 (spill = abort).
// C/D mapping (verified r1+): col = lane&15, row = (lane>>4)*4 + reg.
// ---------------------------------------------------------------------------
#define GBM 128
#define GBN 256
#define GBK 32

__device__ __forceinline__ void gld_lds16(const void* g, void* l) {
    __builtin_amdgcn_global_load_lds(
        (const __attribute__((address_space(1))) void*)g,
        (__attribute__((address_space(3))) void*)l, 16, 0, 0);
}

__global__ __launch_bounds__(512, 4) void gemm_fused(
    const float* __restrict__ feat1,
    const ushort* __restrict__ interpB,
    const ushort* __restrict__ W1t, const float* __restrict__ b1,
    const ushort* __restrict__ W2pack, const float* __restrict__ b2,
    float* __restrict__ out)
{
    __shared__ ushort pool[GBM * 256];   // 64 KB: phase1 dbuf (2x24KB); then H

    const int tid  = threadIdx.x;
    const int lane = tid & 63;
    const int wid  = tid >> 6;           // 0..7
    const int m0   = blockIdx.x * GBM;
    const int wr   = wid >> 2;           // 0..1
    const int wc   = wid & 3;            // 0..3

    const int rsub = lane >> 2;                    // 0..15 (row in 16-row chunk)
    const int slot = lane & 3;                     // 0..3  (8-ushort slot)
    const int csub = slot * 8;                     // linear LDS slot offset
    const int usw  = (slot ^ (rsub & 3)) * 8;      // swizzled SOURCE slot offset

    const int kgrp = (lane >> 4) * 8;
    const int rl   = lane & 15;
    const int ksw  = kgrp ^ ((rl & 3) << 3);       // swizzled read slot
    const int cl   = lane & 15;
    const int rgrp = (lane >> 4) * 4;

    // stage one K-step of A (8 chunks) + W1t (16 chunks) into buffer `buf`.
    auto stageAB = [&](int k0, int buf) {
        ushort* sAb = pool + buf * 12288;          // 8KB A
        ushort* sBb = sAb + 4096;                  // 16KB B
#pragma unroll
        for (int c = 0; c < 3; ++c) {
            const int cid = wid * 3 + c;           // 0..23
            if (cid < 8) {
                const int r = m0 + cid * 16 + rsub;
                if (k0 < C1C) {
                    const float* src = feat1 + (size_t)r * C1C + k0 + usw;
                    float4 u = ((const float4*)src)[0];
                    float4 v = ((const float4*)src)[1];
                    ushortx8 t;
                    t[0] = f2bf(u.x); t[1] = f2bf(u.y); t[2] = f2bf(u.z); t[3] = f2bf(u.w);
                    t[4] = f2bf(v.x); t[5] = f2bf(v.y); t[6] = f2bf(v.z); t[7] = f2bf(v.w);
                    *(ushortx8*)&sAb[cid * 512 + rsub * 32 + csub] = t;
                } else {
                    gld_lds16(interpB + (size_t)r * C2C + (k0 - C1C) + usw, &sAb[cid * 512]);
                }
            } else {
                const int bi = cid - 8;
                const int r = bi * 16 + rsub;
                gld_lds16(W1t + (size_t)r * KIN + k0 + usw, &sBb[bi * 512]);
            }
        }
    };

    // ---------------- phase 1: acc1 = A @ W1t^T (double-buffered) ----------
    f32x4 acc1[4][4];
#pragma unroll
    for (int i = 0; i < 4; ++i)
#pragma unroll
        for (int j = 0; j < 4; ++j) acc1[i][j] = (f32x4){0.f, 0.f, 0.f, 0.f};

    int cur = 0;
    stageAB(0, 0);
    for (int k0 = 0; k0 < KIN; k0 += GBK) {
        __syncthreads();                 // stage(k0->cur) done; prev reads done
        if (k0 + GBK < KIN) stageAB(k0 + GBK, cur ^ 1);

        const ushort* sAb = pool + cur * 12288;
        const ushort* sBb = sAb + 4096;
        short8 af[4], bf[4];
#pragma unroll
        for (int i = 0; i < 4; ++i) {
            af[i] = *(const short8*)&sAb[(wr * 64 + i * 16 + rl) * GBK + ksw];
            bf[i] = *(const short8*)&sBb[(wc * 64 + i * 16 + rl) * GBK + ksw];
        }
#pragma unroll
        for (int i = 0; i < 4; ++i)
#pragma unroll
            for (int j = 0; j < 4; ++j)
                acc1[i][j] = __builtin_amdgcn_mfma_f32_16x16x32_bf16(
                    af[i], bf[j], acc1[i][j], 0, 0, 0);
        cur ^= 1;
    }
    __syncthreads();                     // all phase-1 LDS reads done (pool reuse)

    // issue phase-2 first B-frags early (hide L2 latency under H writes)
    short8 bfc[4], bfn[4];
#pragma unroll
    for (int j = 0; j < 4; ++j)
        bfc[j] = *(const short8*)&W2pack[(size_t)(0 * 16 + wc * 4 + j) * 512 + lane * 8];

    // ---------------- transition: H = relu(acc1+b1) -> LDS (bf16) ----------
#pragma unroll
    for (int j = 0; j < 4; ++j) {
        const int c = wc * 64 + j * 16 + cl;
        const float bv = b1[c];
        const int u = c >> 3, sub = c & 7;
#pragma unroll
        for (int i = 0; i < 4; ++i) {
#pragma unroll
            for (int rr = 0; rr < 4; ++rr) {
                const int r = wr * 64 + i * 16 + rgrp + rr;
                const float v = fmaxf(acc1[i][j][rr] + bv, 0.f);
                pool[r * 256 + ((u ^ (r & 31)) << 3) + sub] = f2bf(v);
            }
        }
    }
    __syncthreads();                     // H complete

    // ---------------- phase 2: out = relu(H @ W2^T + b2), barrier-free -----
    f32x4 acc2[4][4];
#pragma unroll
    for (int i = 0; i < 4; ++i)
#pragma unroll
        for (int j = 0; j < 4; ++j) acc2[i][j] = (f32x4){0.f, 0.f, 0.f, 0.f};

    for (int s = 0; s < 8; ++s) {
        if (s < 7) {
#pragma unroll
            for (int j = 0; j < 4; ++j)
                bfn[j] = *(const short8*)&W2pack[(size_t)((s + 1) * 16 + wc * 4 + j) * 512 + lane * 8];
        }
        const int ub = s * 4 + (lane >> 4);        // H unit index 0..31
        short8 af[4];
#pragma unroll
        for (int i = 0; i < 4; ++i) {
            const int r = wr * 64 + i * 16 + rl;
            af[i] = *(const short8*)&pool[r * 256 + ((ub ^ (r & 31)) << 3)];
        }
#pragma unroll
        for (int i = 0; i < 4; ++i)
#pragma unroll
            for (int j = 0; j < 4; ++j)
                acc2[i][j] = __builtin_amdgcn_mfma_f32_16x16x32_bf16(
                    af[i], bfc[j], acc2[i][j], 0, 0, 0);
#pragma unroll
        for (int j = 0; j < 4; ++j) bfc[j] = bfn[j];
    }

    // ---------------- epilogue: bias + relu -> f32 out ---------------------
#pragma unroll
    for (int j = 0; j < 4; ++j) {
        const int col = wc * 64 + j * 16 + cl;
        const float bv = b2[col];
#pragma unroll
        for (int i = 0; i < 4; ++i) {
            const int rowb = m0 + wr * 64 + i * 16 + rgrp;
#pragma unroll
            for (int rr = 0; rr < 4; ++rr) {
                out[(size_t)(rowb + rr) * OUTC + col] =
                    fmaxf(acc2[i][j][rr] + bv, 0.f);
            }
        }
    }
}

// ---------------------------------------------------------------------------
// ws layout (bytes): interpB 33.5M @0 | W1t @33554432 | W2pack @33751040
// ---------------------------------------------------------------------------
extern "C" void kernel_launch(void* const* d_in, const int* in_sizes, int n_in,
                              void* d_out, int out_size, void* d_ws, size_t ws_size,
                              hipStream_t stream) {
    const float* xyz1  = (const float*)d_in[0];
    const float* xyz2  = (const float*)d_in[1];
    const float* feat1 = (const float*)d_in[2];
    const float* feat2 = (const float*)d_in[3];
    const float* W1    = (const float*)d_in[4];
    const float* b1    = (const float*)d_in[5];
    const float* W2    = (const float*)d_in[6];
    const float* b2    = (const float*)d_in[7];
    float* out = (float*)d_out;

    char* ws = (char*)d_ws;
    ushort* interpB = (ushort*)(ws);
    ushort* W1t     = (ushort*)(ws + 33554432);
    ushort* W2pack  = (ushort*)(ws + 33751040);

    const int M = BB * NN;  // 65536

    weights_prep_kernel<<<(KIN * OUTC + OUTC * OUTC + 255) / 256, 256, 0, stream>>>(
        W1, W1t, W2, W2pack);

    knn_gather_kernel<<<512, 1024, 0, stream>>>(xyz1, xyz2, feat2, interpB);

    gemm_fused<<<M / GBM, 512, 0, stream>>>(feat1, interpB,
                                            W1t, b1, W2pack, b2, out);
}